// Round 10
// baseline (88.376 us; speedup 1.0000x reference)
//
#include <hip/hip_runtime.h>
#include <hip/hip_bf16.h>

typedef __attribute__((ext_vector_type(8))) short short8;
typedef __attribute__((ext_vector_type(4))) float f32x4;

#define N_BATCH 8
#define N_ROWS 32768
#define DDIM 128
#define KSLOT 64
#define EH 128
#define TPB 4                  // tiles per block
#define BLK_PER_B 128          // 512 tiles / TPB
#define SCALE 0.08838834764831845f

__device__ inline unsigned short f2bf(float f){
  unsigned int u = __builtin_bit_cast(unsigned int, f);
  u = (u + 0x7FFFu + ((u >> 16) & 1u)) >> 16;
  return (unsigned short)u;
}

__device__ inline unsigned int pk2bf(float lo, float hi){
  __hip_bfloat162 h = __float22bfloat162_rn(float2{lo, hi});
  unsigned int u;
  __builtin_memcpy(&u, &h, 4);
  return u;
}

// lgkm-only barrier: protects LDS produce->consume without draining vmcnt,
// so cross-tile global prefetch stays in flight across the barrier.
__device__ inline void lds_barrier(){
  asm volatile("s_waitcnt lgkmcnt(0)" ::: "memory");
  __builtin_amdgcn_s_barrier();
}

// ---- prep: qk[b][s][d] = scale * (S[b,s,:]@Wq) @ Wk^T, bf16 ----
__global__ void prep_qk_kernel(const float* __restrict__ S, const float* __restrict__ Wq,
                               const float* __restrict__ Wk, unsigned short* __restrict__ qk){
  int bs = blockIdx.x;             // 0..511 = b*64 + slot
  __shared__ float srow[128];
  __shared__ float qrow[128];
  int t = threadIdx.x;             // 128 threads
  srow[t] = S[bs * 128 + t];
  __syncthreads();
  float acc = 0.f;
  #pragma unroll 8
  for(int h = 0; h < 128; ++h) acc += srow[h] * Wq[h * 128 + t];   // q[s,e=t]
  qrow[t] = acc;
  __syncthreads();
  float acc2 = 0.f;
  #pragma unroll 8
  for(int e = 0; e < 128; ++e) acc2 += qrow[e] * Wk[t * 128 + e];  // qk[s,d=t]
  qk[bs * 128 + t] = f2bf(acc2 * SCALE);
}

// ---- main fused kernel: TPB tiles per block, register-prefetched ----
__global__ __launch_bounds__(256, 4) void sse_main_kernel(
    const float* __restrict__ X, const unsigned short* __restrict__ qk,
    float* __restrict__ partials)
{
  __shared__ unsigned short Xt[128][70];   // X tile transposed [d][row]
  __shared__ unsigned short WTs[64][70];   // W transposed [slot][row]

  const int tid  = threadIdx.x;
  const int wave = tid >> 6;
  const int lane = tid & 63;
  const int l15  = lane & 15;
  const int g    = lane >> 4;

  const int b  = blockIdx.x / BLK_PER_B;
  const int tb = blockIdx.x % BLK_PER_B;

  const float* Xb = X + (size_t)b * N_ROWS * DDIM;
  const unsigned short* qkb = qk + b * KSLOT * EH;

  f32x4 sacc[8];   // T[slot=wave*16+g*4+r][d=et*16+l15]
  #pragma unroll
  for(int i = 0; i < 8; ++i) sacc[i] = {0.f, 0.f, 0.f, 0.f};

  // X strip base for this wave: row = tile*64 + wave*16 + l15
  const float* xw = Xb + (size_t)(tb * TPB * 64 + wave * 16 + l15) * DDIM + g * 8;

  f32x4 xa[8];     // current tile's raw X (2 f32x4 per step)
  #pragma unroll
  for(int s2 = 0; s2 < 4; ++s2){
    xa[2*s2]   = *reinterpret_cast<const f32x4*>(xw + s2 * 32);
    xa[2*s2+1] = *reinterpret_cast<const f32x4*>(xw + s2 * 32 + 4);
  }

  #pragma unroll
  for(int tt = 0; tt < TPB; ++tt){
    f32x4 xn[8];
    if(tt + 1 < TPB){
      const float* xp = xw + (size_t)(tt + 1) * 64 * DDIM;
      #pragma unroll
      for(int s2 = 0; s2 < 4; ++s2){
        xn[2*s2]   = *reinterpret_cast<const f32x4*>(xp + s2 * 32);
        xn[2*s2+1] = *reinterpret_cast<const f32x4*>(xp + s2 * 32 + 4);
      }
    }

    // ---- pack bf16 A-frags (v_cvt_pk path) + transposed store to Xt ----
    short8 a4[4];
    #pragma unroll
    for(int step = 0; step < 4; ++step){
      f32x4 x0 = xa[2*step], x1 = xa[2*step+1];
      union { short8 s; unsigned int u[4]; } pk;
      pk.u[0] = pk2bf(x0[0], x0[1]);
      pk.u[1] = pk2bf(x0[2], x0[3]);
      pk.u[2] = pk2bf(x1[0], x1[1]);
      pk.u[3] = pk2bf(x1[2], x1[3]);
      a4[step] = pk.s;
      #pragma unroll
      for(int j = 0; j < 8; ++j)
        Xt[step * 32 + g * 8 + j][wave * 16 + l15] = (unsigned short)a4[step][j];
    }

    // ---- phase A: M-tile = X @ qk^T ----
    f32x4 macc[4];
    #pragma unroll
    for(int i = 0; i < 4; ++i) macc[i] = {0.f,0.f,0.f,0.f};
    #pragma unroll
    for(int step = 0; step < 4; ++step){
      #pragma unroll
      for(int st = 0; st < 4; ++st){
        short8 bq = *reinterpret_cast<const short8*>(qkb + (st * 16 + l15) * EH + step * 32 + g * 8);
        macc[st] = __builtin_amdgcn_mfma_f32_16x16x32_bf16(a4[step], bq, macc[st], 0, 0, 0);
      }
    }

    // ---- sigmoid + eps, normalize over 64 slots, W^T -> LDS ----
    float att[4][4];
    float rinv[4];
    #pragma unroll
    for(int st = 0; st < 4; ++st){
      #pragma unroll
      for(int r = 0; r < 4; ++r)
        att[st][r] = __builtin_amdgcn_rcpf(1.f + __expf(-macc[st][r])) + 1e-8f;
    }
    #pragma unroll
    for(int r = 0; r < 4; ++r){
      float s = att[0][r] + att[1][r] + att[2][r] + att[3][r];
      s += __shfl_xor(s, 1); s += __shfl_xor(s, 2);
      s += __shfl_xor(s, 4); s += __shfl_xor(s, 8);
      rinv[r] = __builtin_amdgcn_rcpf(s);
    }
    #pragma unroll
    for(int st = 0; st < 4; ++st){
      union { unsigned int u[2]; uint2 v; } wp;
      wp.u[0] = pk2bf(att[st][0] * rinv[0], att[st][1] * rinv[1]);
      wp.u[1] = pk2bf(att[st][2] * rinv[2], att[st][3] * rinv[3]);
      *reinterpret_cast<uint2*>(&WTs[st * 16 + l15][wave * 16 + g * 4]) = wp.v;
    }
    lds_barrier();   // Xt + WTs visible; prefetch loads stay in flight

    // ---- phase B: T += W^T @ X ----
    #pragma unroll
    for(int ns = 0; ns < 2; ++ns){
      short8 af = *reinterpret_cast<const short8*>(&WTs[wave * 16 + l15][ns * 32 + g * 8]);
      #pragma unroll
      for(int et = 0; et < 8; ++et){
        short8 bf = *reinterpret_cast<const short8*>(&Xt[et * 16 + l15][ns * 32 + g * 8]);
        sacc[et] = __builtin_amdgcn_mfma_f32_16x16x32_bf16(af, bf, sacc[et], 0, 0, 0);
      }
    }
    lds_barrier();   // phase-B reads done before next tile's writes

    if(tt + 1 < TPB){
      #pragma unroll
      for(int j = 0; j < 8; ++j) xa[j] = xn[j];
    }
  }

  // ---- write per-block partial T [64 slot][128 d] f32 ----
  float* po = partials + (size_t)blockIdx.x * (KSLOT * EH);
  #pragma unroll
  for(int et = 0; et < 8; ++et){
    #pragma unroll
    for(int r = 0; r < 4; ++r)
      po[(wave * 16 + g * 4 + r) * EH + et * 16 + l15] = sacc[et][r];
  }
}

// ---- reduce: T[b][s][:] = sum over block-partials, then out = T @ Wv ----
__global__ void reduce_kernel(const float* __restrict__ partials,
                              const float* __restrict__ Wv, float* __restrict__ out){
  int bs = blockIdx.x;             // 0..511 = b*64 + slot
  int b  = bs >> 6;
  int s  = bs & 63;
  __shared__ float Tl[128];
  int t = threadIdx.x;             // 128 threads = d, then e
  const float* pb = partials + (size_t)b * BLK_PER_B * (KSLOT * EH) + s * EH + t;
  float acc = 0.f;
  #pragma unroll 8
  for(int i = 0; i < BLK_PER_B; ++i)
    acc += pb[(size_t)i * (KSLOT * EH)];
  Tl[t] = acc;
  __syncthreads();
  float o = 0.f;
  #pragma unroll 8
  for(int d = 0; d < 128; ++d) o += Tl[d] * Wv[d * 128 + t];
  out[bs * 128 + t] = o;
}

extern "C" void kernel_launch(void* const* d_in, const int* in_sizes, int n_in,
                              void* d_out, int out_size, void* d_ws, size_t ws_size,
                              hipStream_t stream){
  const float* X  = (const float*)d_in[0];
  const float* S  = (const float*)d_in[1];
  const float* Wk = (const float*)d_in[2];
  const float* Wq = (const float*)d_in[3];
  const float* Wv = (const float*)d_in[4];
  float* out = (float*)d_out;

  char* ws = (char*)d_ws;
  unsigned short* qk = (unsigned short*)(ws);           // 128 KB
  float* partials    = (float*)(ws + 131072);           // 1024 * 32 KB = 33.5 MB

  hipLaunchKernelGGL(prep_qk_kernel, dim3(512), dim3(128), 0, stream, S, Wq, Wk, qk);
  hipLaunchKernelGGL(sse_main_kernel, dim3(N_BATCH * BLK_PER_B), dim3(256), 0, stream,
                     X, qk, partials);
  hipLaunchKernelGGL(reduce_kernel, dim3(512), dim3(128), 0, stream, partials, Wv, out);
}

// Round 11
// 55.879 us; speedup vs baseline: 1.5816x; 1.5816x over previous
//
#include <hip/hip_runtime.h>
#include <hip/hip_bf16.h>

typedef __attribute__((ext_vector_type(8))) short short8;
typedef __attribute__((ext_vector_type(4))) float f32x4;

#define N_BATCH 8
#define N_ROWS 32768
#define DDIM 128
#define KSLOT 64
#define EH 128
#define TPB 8                  // tiles per block
#define BLK_PER_B 64           // 512 tiles / TPB
#define SCALE 0.08838834764831845f

__device__ inline unsigned short f2bf(float f){
  unsigned int u = __builtin_bit_cast(unsigned int, f);
  u = (u + 0x7FFFu + ((u >> 16) & 1u)) >> 16;
  return (unsigned short)u;
}

__device__ inline unsigned int pk2bf(float lo, float hi){
  __hip_bfloat162 h = __float22bfloat162_rn(float2{lo, hi});
  unsigned int u;
  __builtin_memcpy(&u, &h, 4);
  return u;
}

// lgkm-only barrier: protects LDS produce->consume without draining vmcnt,
// so cross-tile global prefetch stays in flight across the barrier.
__device__ inline void lds_barrier(){
  asm volatile("s_waitcnt lgkmcnt(0)" ::: "memory");
  __builtin_amdgcn_s_barrier();
}

// ---- prep: qk[b][s][d] = scale * (S[b,s,:]@Wq) @ Wk^T, bf16 ----
__global__ void prep_qk_kernel(const float* __restrict__ S, const float* __restrict__ Wq,
                               const float* __restrict__ Wk, unsigned short* __restrict__ qk){
  int bs = blockIdx.x;             // 0..511 = b*64 + slot
  __shared__ float srow[128];
  __shared__ float qrow[128];
  int t = threadIdx.x;             // 128 threads
  srow[t] = S[bs * 128 + t];
  __syncthreads();
  float acc = 0.f;
  #pragma unroll 8
  for(int h = 0; h < 128; ++h) acc += srow[h] * Wq[h * 128 + t];   // q[s,e=t]
  qrow[t] = acc;
  __syncthreads();
  float acc2 = 0.f;
  #pragma unroll 8
  for(int e = 0; e < 128; ++e) acc2 += qrow[e] * Wk[t * 128 + e];  // qk[s,d=t]
  qk[bs * 128 + t] = f2bf(acc2 * SCALE);
}

// ---- main fused kernel: all global accesses lane-contiguous ----
__global__ __launch_bounds__(256, 2) void sse_main_kernel(
    const float* __restrict__ X, const unsigned short* __restrict__ qkg,
    float* __restrict__ partials)
{
  __shared__ unsigned short qs[64][136];   // qk staged   (272B rows: aligned, odd 16B-mult)
  __shared__ unsigned short Xs[64][136];   // X row-major [n][d]
  __shared__ unsigned short Xt[128][70];   // X transposed [d][n] (legacy layout)
  __shared__ unsigned short WTs[64][72];   // W^T [slot][n] (144B rows: aligned)

  const int tid  = threadIdx.x;
  const int wave = tid >> 6;
  const int lane = tid & 63;
  const int l15  = lane & 15;
  const int g    = lane >> 4;
  const int l31  = lane & 31;
  const int half = lane >> 5;

  const int b  = blockIdx.x / BLK_PER_B;
  const int tb = blockIdx.x % BLK_PER_B;

  const float* Xb = X + (size_t)b * N_ROWS * DDIM;
  const unsigned short* qkb = qkg + b * KSLOT * EH;

  // ---- stage qk (16 KB) with fully coalesced loads ----
  #pragma unroll
  for(int i = 0; i < 4; ++i){
    int o = (i * 256 + tid) * 8;           // ushort offset 0..8191
    *reinterpret_cast<short8*>(&qs[o >> 7][o & 127]) =
        *reinterpret_cast<const short8*>(qkb + o);
  }

  f32x4 sacc[8];   // T[slot=wave*16+g*4+r][d=et*16+l15]
  #pragma unroll
  for(int i = 0; i < 8; ++i) sacc[i] = {0.f, 0.f, 0.f, 0.f};

  // coalesced X base: wave's 16-row strip, lane*16B within 1KB chunks
  const float* xw = Xb + (size_t)(tb * TPB * 64 + wave * 16) * DDIM + lane * 4;

  f32x4 xa[8];     // 8 contiguous 1KB chunks = 16 rows
  #pragma unroll
  for(int c = 0; c < 8; ++c)
    xa[c] = *reinterpret_cast<const f32x4*>(xw + c * 256);

  lds_barrier();   // qs visible to all waves; xa loads stay in flight

  const int wr0 = wave * 16;

  #pragma unroll
  for(int tt = 0; tt < TPB; ++tt){

    // ---- pack xa -> Xs (row-major, b64) + Xt (transposed, scalar) ----
    #pragma unroll
    for(int c = 0; c < 8; ++c){
      const int n = wr0 + 2 * c + half;    // local n row (0..63)
      unsigned int u0 = pk2bf(xa[c][0], xa[c][1]);
      unsigned int u1 = pk2bf(xa[c][2], xa[c][3]);
      ushort4 p;
      __builtin_memcpy(&p, &u0, 4);
      __builtin_memcpy(reinterpret_cast<char*>(&p) + 4, &u1, 4);
      *reinterpret_cast<ushort4*>(&Xs[n][4 * l31]) = p;
      Xt[4 * l31 + 0][n] = p.x;
      Xt[4 * l31 + 1][n] = p.y;
      Xt[4 * l31 + 2][n] = p.z;
      Xt[4 * l31 + 3][n] = p.w;
    }

    // ---- prefetch next tile into xa (xa dead after pack) ----
    if(tt + 1 < TPB){
      const float* xp = xw + (size_t)(tt + 1) * 64 * DDIM;
      #pragma unroll
      for(int c = 0; c < 8; ++c)
        xa[c] = *reinterpret_cast<const f32x4*>(xp + c * 256);
    }

    // ---- phase A: M = X @ qk^T (A from Xs own strip, B from qs) ----
    f32x4 macc[4];
    #pragma unroll
    for(int i = 0; i < 4; ++i) macc[i] = {0.f,0.f,0.f,0.f};
    #pragma unroll
    for(int step = 0; step < 4; ++step){
      short8 a = *reinterpret_cast<const short8*>(&Xs[wr0 + l15][step * 32 + g * 8]);
      #pragma unroll
      for(int st = 0; st < 4; ++st){
        short8 bq = *reinterpret_cast<const short8*>(&qs[st * 16 + l15][step * 32 + g * 8]);
        macc[st] = __builtin_amdgcn_mfma_f32_16x16x32_bf16(a, bq, macc[st], 0, 0, 0);
      }
    }

    // ---- sigmoid + eps, normalize over 64 slots, W^T -> LDS ----
    float att[4][4];
    float rinv[4];
    #pragma unroll
    for(int st = 0; st < 4; ++st){
      #pragma unroll
      for(int r = 0; r < 4; ++r)
        att[st][r] = __builtin_amdgcn_rcpf(1.f + __expf(-macc[st][r])) + 1e-8f;
    }
    #pragma unroll
    for(int r = 0; r < 4; ++r){
      float s = att[0][r] + att[1][r] + att[2][r] + att[3][r];
      s += __shfl_xor(s, 1); s += __shfl_xor(s, 2);
      s += __shfl_xor(s, 4); s += __shfl_xor(s, 8);
      rinv[r] = __builtin_amdgcn_rcpf(s);
    }
    #pragma unroll
    for(int st = 0; st < 4; ++st){
      unsigned int u0 = pk2bf(att[st][0] * rinv[0], att[st][1] * rinv[1]);
      unsigned int u1 = pk2bf(att[st][2] * rinv[2], att[st][3] * rinv[3]);
      ushort4 wp;
      __builtin_memcpy(&wp, &u0, 4);
      __builtin_memcpy(reinterpret_cast<char*>(&wp) + 4, &u1, 4);
      *reinterpret_cast<ushort4*>(&WTs[st * 16 + l15][wave * 16 + g * 4]) = wp;
    }
    lds_barrier();   // Xt + WTs complete across waves; xa prefetch stays in flight

    // ---- phase B: T += W^T @ X ----
    #pragma unroll
    for(int ns = 0; ns < 2; ++ns){
      short8 af = *reinterpret_cast<const short8*>(&WTs[wr0 + l15][ns * 32 + g * 8]);
      #pragma unroll
      for(int et = 0; et < 8; ++et){
        short8 bf = *reinterpret_cast<const short8*>(&Xt[et * 16 + l15][ns * 32 + g * 8]);
        sacc[et] = __builtin_amdgcn_mfma_f32_16x16x32_bf16(af, bf, sacc[et], 0, 0, 0);
      }
    }
    lds_barrier();   // phase-B reads done before next tile overwrites
  }

  // ---- write per-block partial T [64 slot][128 d] f32 ----
  float* po = partials + (size_t)blockIdx.x * (KSLOT * EH);
  #pragma unroll
  for(int et = 0; et < 8; ++et){
    #pragma unroll
    for(int r = 0; r < 4; ++r)
      po[(wave * 16 + g * 4 + r) * EH + et * 16 + l15] = sacc[et][r];
  }
}

// ---- reduce: T[b][s][:] = sum over 64 block-partials, then out = T @ Wv ----
__global__ void reduce_kernel(const float* __restrict__ partials,
                              const float* __restrict__ Wv, float* __restrict__ out){
  int bs = blockIdx.x;             // 0..511 = b*64 + slot
  int b  = bs >> 6;
  int s  = bs & 63;
  __shared__ float Tl[128];
  int t = threadIdx.x;             // 128 threads = d, then e
  const float* pb = partials + (size_t)b * BLK_PER_B * (KSLOT * EH) + s * EH + t;
  float acc = 0.f;
  #pragma unroll 8
  for(int i = 0; i < BLK_PER_B; ++i)
    acc += pb[(size_t)i * (KSLOT * EH)];
  Tl[t] = acc;
  __syncthreads();
  float o = 0.f;
  #pragma unroll 8
  for(int d = 0; d < 128; ++d) o += Tl[d] * Wv[d * 128 + t];
  out[bs * 128 + t] = o;
}

extern "C" void kernel_launch(void* const* d_in, const int* in_sizes, int n_in,
                              void* d_out, int out_size, void* d_ws, size_t ws_size,
                              hipStream_t stream){
  const float* X  = (const float*)d_in[0];
  const float* S  = (const float*)d_in[1];
  const float* Wk = (const float*)d_in[2];
  const float* Wq = (const float*)d_in[3];
  const float* Wv = (const float*)d_in[4];
  float* out = (float*)d_out;

  char* ws = (char*)d_ws;
  unsigned short* qk = (unsigned short*)(ws);           // 128 KB
  float* partials    = (float*)(ws + 131072);           // 512 * 32 KB = 16.8 MB

  hipLaunchKernelGGL(prep_qk_kernel, dim3(512), dim3(128), 0, stream, S, Wq, Wk, qk);
  hipLaunchKernelGGL(sse_main_kernel, dim3(N_BATCH * BLK_PER_B), dim3(256), 0, stream,
                     X, qk, partials);
  hipLaunchKernelGGL(reduce_kernel, dim3(512), dim3(128), 0, stream, partials, Wv, out);
}